// Round 6
// baseline (212.554 us; speedup 1.0000x reference)
//
#include <hip/hip_runtime.h>
#include <math.h>

// Problem constants (from reference)
#define BATCH     2
#define NLAB      256            // 64 bifs * 4 stubs
#define VOX       (192*192*192)  // 7,077,888 voxels per batch
#define TEMP      0.2f
#define GRIDX     768            // blocks per batch (1536 blocks = 6/CU even)
#define NITER     ((VOX/4)/(GRIDX*256))   // = 9 exact
#define STRIDE    (GRIDX*256)
#define NPART     16             // reduce parts per batch

// Packed slot: value = sum_fg + STEP*count. Per block 9216 voxels (~36/bin,
// max ~150): packed <= ~600K << 2^24 -> count decodes exactly; fg rounding
// noise ~1e-4 relative on batch-bin means (threshold 1e-2; R1/R3/R5 absmax 0.0).
#define STEP      4096.0f
#define INV_STEP  (1.0f/4096.0f)

typedef unsigned int u32;
typedef __attribute__((ext_vector_type(8))) short bf16x8;   // 8 bf16 (4 VGPRs)
typedef __attribute__((ext_vector_type(4))) float f32x4;    // MFMA C/D
union FragU { uint4 u; bf16x8 v; };

// fg = sigmoid(p1-p0) (C==2 softmax ch1), RNE -> bf16 in low 16 bits.
__device__ __forceinline__ u32 fgbf16(float pa, float pc) {
    const float fg = __builtin_amdgcn_rcpf(1.0f + __expf(pa - pc));
    u32 bits = __float_as_uint(fg);
    bits += 0x7FFFu + ((bits >> 16) & 1u);            // RNE to bf16
    return bits >> 16;
}

// one-hot masks for a voxel's label: hm = 1<<hi4, lm = 1<<lo4 (bin=hi*16+lo)
__device__ __forceinline__ void voxmask(float pl, u32& hm, u32& lmm) {
    const u32 lab = ((u32)(int)(pl + 0.5f)) & 255u;
    hm  = 1u << (lab >> 4);
    lmm = 1u << (lab & 15u);
}

// Fragment build, one voxel-PAIR (2 K-slots): 8 VALU ops (R5-verified,
// absmax 0.0). whi/wlo pair-packed one-hot masks; fp packed bf16 fg pair.
#define PAIRH(whi, wlo, fp, aw, b1w, b2w) do {                              \
    const u32 _h = ((whi) >> mlane) & 0x10001u;                             \
    const u32 _l = ((wlo) >> mlane) & 0x10001u;                             \
    aw  = __umul24(_h, 0x3F80u);                                            \
    b1w = __umul24(_l, 0x3F80u);                                            \
    b2w = (fp) & __umul24(_l, 0xFFFFu);                                     \
} while (0)

// Pack one iteration's 4 voxels into staged words.
#define PACKIT(av, cv, lv, WHIA, WLOA, WHIB, WLOB, FGA, FGB) do {           \
    u32 hm0, lm0, hm1, lm1, hm2, lm2, hm3, lm3;                             \
    voxmask((lv).x, hm0, lm0);                                              \
    voxmask((lv).y, hm1, lm1);                                              \
    voxmask((lv).z, hm2, lm2);                                              \
    voxmask((lv).w, hm3, lm3);                                              \
    WHIA = hm0 | (hm1 << 16);                                               \
    WLOA = lm0 | (lm1 << 16);                                               \
    WHIB = hm2 | (hm3 << 16);                                               \
    WLOB = lm2 | (lm3 << 16);                                               \
    FGA  = fgbf16((av).x, (cv).x) | (fgbf16((av).y, (cv).y) << 16);         \
    FGB  = fgbf16((av).z, (cv).z) | (fgbf16((av).w, (cv).w) << 16);         \
} while (0)

// ---------------------------------------------------------------------------
// Kernel 1: histogram via one-hot outer-product MFMA (no atomics).
// Per 32-voxel tile: counts += Phi^T*Plo, sums += Phi^T*(fg*Plo) via
// 16x16x32 bf16 MFMA; wave-private LDS staging; broadcast uint4 reads.
// R5 post-mortem: wall = VALU(30us) + LDS(28us) SERIAL — the per-tile
// ds_read -> build chain was never pipelined (VGPR=32: no lookahead regs).
// This version: (a) explicit 2-deep tile-read rotation (issue tile t+1's 3
// ds_read_b128 before building tile t); (b) 1-iter pack skew (stage it+1
// into the other dbuf half before the tile loop of it) so the ds stream
// never drains; (c) __launch_bounds__(256,6) grants ~84 VGPRs at the
// 6-block/CU occupancy the grid already has.
// ---------------------------------------------------------------------------
__global__ __launch_bounds__(256, 6) void histo_kernel(
    const float* __restrict__ pred,     // [B,2,V]
    const float* __restrict__ labmap,   // [B,1,V]
    float* __restrict__ ws_slots)       // [B*GRIDX][256] packed per-block hist
{
    __shared__ __align__(16) u32 s_iv[4][2][256];   // (whi,wlo) per pair
    __shared__ __align__(16) u32 s_fg[4][2][128];   // packed fg pairs

    const int b    = blockIdx.y;
    const int tid  = threadIdx.x;
    const int w    = tid >> 6;          // wave 0..3
    const int lane = tid & 63;
    const u32 mlane = (u32)(lane & 15); // A row / B col owned by this lane
    const int g    = lane >> 4;         // K-group 0..3

    const float4* p0 = (const float4*)(pred + (size_t)b * 2 * VOX);
    const float4* p1 = (const float4*)(pred + (size_t)b * 2 * VOX + VOX);
    const float4* lm = (const float4*)(labmap + (size_t)b * VOX);

    f32x4 accC = {0.f, 0.f, 0.f, 0.f};  // counts C[16][16]
    f32x4 accS = {0.f, 0.f, 0.f, 0.f};  // fg sums C[16][16]

    const int base = blockIdx.x * 256 + tid;

    // --- prologue: stage iter 0; hold iter 1's data in regs ---
    {
        const float4 a0 = p0[base], c0 = p1[base], l0 = lm[base];
        u32 whiA, wloA, whiB, wloB, fgA, fgB;
        PACKIT(a0, c0, l0, whiA, wloA, whiB, wloB, fgA, fgB);
        *(uint4*)(&s_iv[w][0][0] + (lane << 2)) =
            make_uint4(whiA, wloA, whiB, wloB);
        *(uint2*)(&s_fg[w][0][0] + (lane << 1)) = make_uint2(fgA, fgB);
    }
    float4 a1 = p0[base + STRIDE], c1 = p1[base + STRIDE], l1 = lm[base + STRIDE];

    for (int it = 0; it < NITER; ++it) {
        // (b) pack skew: stage iter it+1 into the other dbuf half now.
        if (it + 1 < NITER) {
            u32 whiA, wloA, whiB, wloB, fgA, fgB;
            PACKIT(a1, c1, l1, whiA, wloA, whiB, wloB, fgA, fgB);
            u32* iv  = &s_iv[w][(it + 1) & 1][0];
            u32* fgp = &s_fg[w][(it + 1) & 1][0];
            *(uint4*)(iv + (lane << 2)) = make_uint4(whiA, wloA, whiB, wloB);
            *(uint2*)(fgp + (lane << 1)) = make_uint2(fgA, fgB);
        }
        // issue iter it+2's global loads (clamped -> unconditional)
        {
            const int nit = (it + 2 < NITER) ? (it + 2) : (NITER - 1);
            const int inx = base + nit * STRIDE;
            a1 = p0[inx]; c1 = p1[inx]; l1 = lm[inx];
        }

        // (a) tile loop over buf[it&1] with 2-deep read rotation.
        const u32* rp = &s_iv[w][it & 1][0] + (g << 3);
        const u32* rf = &s_fg[w][it & 1][0] + (g << 2);

        uint4 q0 = *(const uint4*)(rp);
        uint4 q1 = *(const uint4*)(rp + 4);
        uint4 fq = *(const uint4*)(rf);
        #pragma unroll
        for (int t = 0; t < 8; ++t) {
            uint4 q0n, q1n, fqn;
            if (t < 7) {   // issue next tile's reads BEFORE building this one
                q0n = *(const uint4*)(rp + (t + 1) * 32);
                q1n = *(const uint4*)(rp + (t + 1) * 32 + 4);
                fqn = *(const uint4*)(rf + (t + 1) * 16);
            }
            u32 a0, a1w, a2, a3, b10, b11, b12, b13, b20, b21, b22, b23;
            PAIRH(q0.x, q0.y, fq.x, a0,  b10, b20);
            PAIRH(q0.z, q0.w, fq.y, a1w, b11, b21);
            PAIRH(q1.x, q1.y, fq.z, a2,  b12, b22);
            PAIRH(q1.z, q1.w, fq.w, a3,  b13, b23);
            FragU A, B1, B2;
            A.u  = make_uint4(a0, a1w, a2, a3);
            B1.u = make_uint4(b10, b11, b12, b13);
            B2.u = make_uint4(b20, b21, b22, b23);
            accC = __builtin_amdgcn_mfma_f32_16x16x32_bf16(A.v, B1.v, accC, 0, 0, 0);
            accS = __builtin_amdgcn_mfma_f32_16x16x32_bf16(A.v, B2.v, accS, 0, 0, 0);
            if (t < 7) { q0 = q0n; q1 = q1n; fq = fqn; }
        }
    }

    // C/D layout (m89-verified): col = lane&15, row = (lane>>4)*4 + reg.
    // bin = row*16 + col. Reuse stage LDS as fold scratch (in-wave ds
    // ordering makes the overwrite safe).
    float* cnt_w = (float*)&s_iv[w][0][0];
    float* sum_w = (float*)&s_iv[w][1][0];
    const int row0 = (lane >> 4) << 2;
    const int colb = lane & 15;
    #pragma unroll
    for (int j = 0; j < 4; ++j) {
        cnt_w[(row0 + j) * 16 + colb] = accC[j];
        sum_w[(row0 + j) * 16 + colb] = accS[j];
    }
    __syncthreads();

    float cs = 0.0f, ss = 0.0f;
    #pragma unroll
    for (int ww = 0; ww < 4; ++ww) {
        cs += ((float*)&s_iv[ww][0][0])[tid];
        ss += ((float*)&s_iv[ww][1][0])[tid];
    }
    ws_slots[((size_t)(b * GRIDX + blockIdx.x)) * NLAB + tid] = ss + STEP * cs;
}

// ---------------------------------------------------------------------------
// Kernel 2: parallel slot reduction. Block r: batch = r/NPART, part = r%NPART;
// 256 threads = bins. Decode + sum GRIDX/NPART slots (coalesced 1KB rows).
// ---------------------------------------------------------------------------
__global__ __launch_bounds__(256) void reduce_kernel(
    const float* __restrict__ ws_slots, // [B*GRIDX][256]
    float* __restrict__ psum,           // [B*NPART][256]
    float* __restrict__ pcnt)           // [B*NPART][256]
{
    const int bin  = threadIdx.x;
    const int b    = blockIdx.x / NPART;
    const int part = blockIdx.x % NPART;
    const int per  = GRIDX / NPART;

    float cs = 0.0f, ss = 0.0f;
    for (int s = part * per; s < (part + 1) * per; ++s) {
        float v = ws_slots[((size_t)(b * GRIDX + s)) * NLAB + bin];
        float c = floorf(v * INV_STEP + 0.5f);   // exact count decode
        cs += c;
        ss += v - c * STEP;                      // packed fg sum
    }
    psum[(size_t)blockIdx.x * NLAB + bin] = ss;
    pcnt[(size_t)blockIdx.x * NLAB + bin] = cs;
}

// ---------------------------------------------------------------------------
// Kernel 3: fold partials, then masked softmin -> scalar loss.
// ---------------------------------------------------------------------------
__global__ __launch_bounds__(256) void scalar_kernel(
    const float* __restrict__ psum,     // [B*NPART][256]
    const float* __restrict__ pcnt,
    float* __restrict__ out)            // [1] loss
{
    __shared__ float s_fsum[BATCH][NLAB];
    __shared__ float s_fcnt[BATCH][NLAB];

    const int tid = threadIdx.x;        // 256 threads = bins

    for (int b = 0; b < BATCH; ++b) {
        float ss = 0.0f, cs = 0.0f;
        for (int p = 0; p < NPART; ++p) {
            ss += psum[(size_t)(b * NPART + p) * NLAB + tid];
            cs += pcnt[(size_t)(b * NPART + p) * NLAB + tid];
        }
        s_fsum[b][tid] = ss;
        s_fcnt[b][tid] = cs;
    }
    __syncthreads();

    if (tid < 64) {
        float total = 0.0f;
        float nbifs = 0.0f;
        if (tid >= 1) {  // bifs 1..63 (reference drops bif 0)
            for (int bb = 0; bb < BATCH; ++bb) {
                float means[3];
                bool  valid[3];
                int   nvalid = 0;
                for (int s = 0; s < 3; ++s) {
                    int lab = tid * 4 + 1 + s;   // stub s+1 (stub 0 dropped)
                    float cnt = s_fcnt[bb][lab];
                    float sum = s_fsum[bb][lab];
                    valid[s] = (cnt >= 1.0f);            // MIN_VOXELS = 1
                    means[s] = sum / fmaxf(cnt, 1.0f);
                    nvalid  += valid[s] ? 1 : 0;
                }
                float logits[3], m = -3e38f;
                for (int s = 0; s < 3; ++s) {
                    logits[s] = valid[s] ? (-means[s] / TEMP) : -1e9f;
                    m = fmaxf(m, logits[s]);
                }
                float e[3], se = 0.0f;
                for (int s = 0; s < 3; ++s) { e[s] = __expf(logits[s] - m); se += e[s]; }
                float score = 0.0f;
                for (int s = 0; s < 3; ++s) {
                    if (valid[s]) score += means[s] * (e[s] / se);
                }
                if (nvalid >= 2) {  // MIN_STUBS = 2
                    total += 1.0f - score;
                    nbifs += 1.0f;
                }
            }
        }
        for (int off = 32; off > 0; off >>= 1) {
            total += __shfl_down(total, off);
            nbifs += __shfl_down(nbifs, off);
        }
        if (tid == 0) {
            out[0] = (nbifs > 0.0f) ? (total / fmaxf(nbifs, 1.0f)) : 0.0f;
        }
    }
}

// ---------------------------------------------------------------------------
extern "C" void kernel_launch(void* const* d_in, const int* in_sizes, int n_in,
                              void* d_out, int out_size, void* d_ws, size_t ws_size,
                              hipStream_t stream) {
    const float* pred = (const float*)d_in[0];   // [B,C,D,H,W] fp32
    const float* lab  = (const float*)d_in[1];   // [B,1,D,H,W] fp32

    float* ws_slots = (float*)d_ws;                          // [B*GRIDX][256]
    float* psum = ws_slots + (size_t)BATCH * GRIDX * NLAB;   // [B*NPART][256]
    float* pcnt = psum + (size_t)BATCH * NPART * NLAB;       // [B*NPART][256]

    dim3 grid(GRIDX, BATCH);
    histo_kernel<<<grid, 256, 0, stream>>>(pred, lab, ws_slots);
    reduce_kernel<<<BATCH * NPART, 256, 0, stream>>>(ws_slots, psum, pcnt);
    scalar_kernel<<<1, 256, 0, stream>>>(psum, pcnt, (float*)d_out);
}

// Round 7
// 207.479 us; speedup vs baseline: 1.0245x; 1.0245x over previous
//
#include <hip/hip_runtime.h>
#include <math.h>

// Problem constants (from reference)
#define BATCH     2
#define NLAB      256            // 64 bifs * 4 stubs
#define VOX       (192*192*192)  // 7,077,888 voxels per batch
#define TEMP      0.2f
#define GRIDX     768            // blocks per batch (1536 blocks = 6/CU even)
#define NITER     ((VOX/4)/(GRIDX*256))   // = 9 exact
#define STRIDE    (GRIDX*256)
#define NPART     16             // reduce parts per batch

// Packed slot: value = sum_fg + STEP*count (R0..R6-verified, absmax 0.0).
#define STEP      4096.0f
#define INV_STEP  (1.0f/4096.0f)

typedef unsigned int u32;
typedef __attribute__((ext_vector_type(2))) u32 u32x2;
typedef __attribute__((ext_vector_type(4))) u32 u32x4;
typedef __attribute__((ext_vector_type(8))) short bf16x8;   // 8 bf16 (4 VGPRs)
typedef __attribute__((ext_vector_type(4))) float f32x4;    // MFMA C/D
union FragU { u32x4 u; bf16x8 v; };

// fg = sigmoid(p1-p0) (C==2 softmax ch1), RNE -> bf16 in low 16 bits.
__device__ __forceinline__ u32 fgbf16(float pa, float pc) {
    const float fg = __builtin_amdgcn_rcpf(1.0f + __expf(pa - pc));
    u32 bits = __float_as_uint(fg);
    bits += 0x7FFFu + ((bits >> 16) & 1u);            // RNE to bf16
    return bits >> 16;
}

// one-hot masks for a voxel's label: hm = 1<<hi4, lm = 1<<lo4 (bin=hi*16+lo)
__device__ __forceinline__ void voxmask(float pl, u32& hm, u32& lmm) {
    const u32 lab = ((u32)(int)(pl + 0.5f)) & 255u;
    hm  = 1u << (lab >> 4);
    lmm = 1u << (lab & 15u);
}

// Fragment build, one voxel-PAIR (2 K-slots): 8 VALU ops (R5-verified).
#define PAIRH(whi, wlo, fp, aw, b1w, b2w) do {                              \
    const u32 _h = ((whi) >> mlane) & 0x10001u;                             \
    const u32 _l = ((wlo) >> mlane) & 0x10001u;                             \
    aw  = __umul24(_h, 0x3F80u);                                            \
    b1w = __umul24(_l, 0x3F80u);                                            \
    b2w = (fp) & __umul24(_l, 0xFFFFu);                                     \
} while (0)

// Pack one iteration's 4 voxels into staged words (R5-verified).
#define PACKIT(av, cv, lv, WHIA, WLOA, WHIB, WLOB, FGA, FGB) do {           \
    u32 hm0, lm0, hm1, lm1, hm2, lm2, hm3, lm3;                             \
    voxmask((lv).x, hm0, lm0);                                              \
    voxmask((lv).y, hm1, lm1);                                              \
    voxmask((lv).z, hm2, lm2);                                              \
    voxmask((lv).w, hm3, lm3);                                              \
    WHIA = hm0 | (hm1 << 16);                                               \
    WLOA = lm0 | (lm1 << 16);                                               \
    WHIB = hm2 | (hm3 << 16);                                               \
    WLOB = lm2 | (lm3 << 16);                                               \
    FGA  = fgbf16((av).x, (cv).x) | (fgbf16((av).y, (cv).y) << 16);         \
    FGB  = fgbf16((av).z, (cv).z) | (fgbf16((av).w, (cv).w) << 16);         \
} while (0)

// --- inline-asm tile pipeline (T3/T4 pattern + rule-#18 fences) ------------
// Tile T's three ds_read_b128 issued as opaque volatile asm; counted
// lgkmcnt waits keep 2 tiles (6 reads) in flight across each build.
// "=&v" early-clobber: dest quads must not alias the address VGPRs.
#define TILE_ISSUE(T, Q0, Q1, FQ)                                           \
    asm volatile("ds_read_b128 %0, %3 offset:%c5\n\t"                       \
                 "ds_read_b128 %1, %3 offset:%c6\n\t"                       \
                 "ds_read_b128 %2, %4 offset:%c7"                           \
                 : "=&v"(Q0), "=&v"(Q1), "=&v"(FQ)                          \
                 : "v"(amask), "v"(afg),                                    \
                   "i"((T)*128), "i"((T)*128 + 16), "i"((T)*64))

// Counted wait + sched_barrier(0): hipcc hoists register-only consumers
// past inline-asm waitcnt ("memory" doesn't order them) — SB0 is the fence.
#define WAITL(N) do {                                                       \
    asm volatile("s_waitcnt lgkmcnt(%c0)" :: "i"(N));                       \
    __builtin_amdgcn_sched_barrier(0);                                      \
} while (0)

#define TILE_BUILD(Q0, Q1, FQ) do {                                         \
    u32 a0, a1w, a2, a3, b10, b11, b12, b13, b20, b21, b22, b23;            \
    PAIRH((Q0).x, (Q0).y, (FQ).x, a0,  b10, b20);                           \
    PAIRH((Q0).z, (Q0).w, (FQ).y, a1w, b11, b21);                           \
    PAIRH((Q1).x, (Q1).y, (FQ).z, a2,  b12, b22);                           \
    PAIRH((Q1).z, (Q1).w, (FQ).w, a3,  b13, b23);                           \
    FragU A, B1, B2;                                                        \
    A.u  = (u32x4){a0, a1w, a2, a3};                                        \
    B1.u = (u32x4){b10, b11, b12, b13};                                     \
    B2.u = (u32x4){b20, b21, b22, b23};                                     \
    accC = __builtin_amdgcn_mfma_f32_16x16x32_bf16(A.v, B1.v, accC, 0,0,0); \
    accS = __builtin_amdgcn_mfma_f32_16x16x32_bf16(A.v, B2.v, accS, 0,0,0); \
} while (0)

// ---------------------------------------------------------------------------
// Kernel 1: histogram via one-hot outer-product MFMA (no atomics).
// R6 post-mortem: hipcc flattens every source-level pipeline (VGPR stuck at
// 20-32; wall = VALU + LDS serial). This version takes the tile loop's
// schedule away from the compiler: volatile-asm ds_read_b128, 3-slot
// rotation, counted lgkmcnt(6/3/0), SB0 after each wait. Build/MFMA/pack/
// staging bit-identical to the R5-verified kernel (absmax 0.0).
// ---------------------------------------------------------------------------
__global__ __launch_bounds__(256, 6) void histo_kernel(
    const float* __restrict__ pred,     // [B,2,V]
    const float* __restrict__ labmap,   // [B,1,V]
    float* __restrict__ ws_slots)       // [B*GRIDX][256] packed per-block hist
{
    __shared__ __align__(16) u32 s_iv[4][2][256];   // (whi,wlo) per pair
    __shared__ __align__(16) u32 s_fg[4][2][128];   // packed fg pairs

    const int b    = blockIdx.y;
    const int tid  = threadIdx.x;
    const int w    = tid >> 6;          // wave 0..3
    const int lane = tid & 63;
    const u32 mlane = (u32)(lane & 15); // A row / B col owned by this lane
    const int g    = lane >> 4;         // K-group 0..3

    const float4* p0 = (const float4*)(pred + (size_t)b * 2 * VOX);
    const float4* p1 = (const float4*)(pred + (size_t)b * 2 * VOX + VOX);
    const float4* lm = (const float4*)(labmap + (size_t)b * VOX);

    f32x4 accC = {0.f, 0.f, 0.f, 0.f};  // counts C[16][16]
    f32x4 accS = {0.f, 0.f, 0.f, 0.f};  // fg sums C[16][16]

    const int base = blockIdx.x * 256 + tid;

    float4 a = p0[base], c = p1[base], l = lm[base];   // iter 0 data

    for (int it = 0; it < NITER; ++it) {
        // prefetch next iter's globals (clamped -> unconditional issue)
        const int nit = (it + 1 < NITER) ? (it + 1) : it;
        const int inx = base + nit * STRIDE;
        const float4 an = p0[inx], cn = p1[inx], ln = lm[inx];

        // pack + stage current iter (wave-private; DS in-order per wave
        // makes write->read of same buffer hazard-free without barriers)
        {
            u32 whiA, wloA, whiB, wloB, fgA, fgB;
            PACKIT(a, c, l, whiA, wloA, whiB, wloB, fgA, fgB);
            u32* iv  = &s_iv[w][it & 1][0];
            u32* fgp = &s_fg[w][it & 1][0];
            *(u32x4*)(iv + (lane << 2))  = (u32x4){whiA, wloA, whiB, wloB};
            *(u32x2*)(fgp + (lane << 1)) = (u32x2){fgA, fgB};
        }
        // fence: staging stores may not sink past the opaque asm reads
        asm volatile("" ::: "memory");

        const u32 amask = (u32)(size_t)&s_iv[w][it & 1][0] + 32u * (u32)g;
        const u32 afg   = (u32)(size_t)&s_fg[w][it & 1][0] + 16u * (u32)g;

        u32x4 qA0, qA1, fA, qB0, qB1, fB, qC0, qC1, fC;
        TILE_ISSUE(0, qA0, qA1, fA);
        TILE_ISSUE(1, qB0, qB1, fB);
        TILE_ISSUE(2, qC0, qC1, fC);            // 9 reads in flight
        WAITL(6); TILE_BUILD(qA0, qA1, fA); TILE_ISSUE(3, qA0, qA1, fA);
        WAITL(6); TILE_BUILD(qB0, qB1, fB); TILE_ISSUE(4, qB0, qB1, fB);
        WAITL(6); TILE_BUILD(qC0, qC1, fC); TILE_ISSUE(5, qC0, qC1, fC);
        WAITL(6); TILE_BUILD(qA0, qA1, fA); TILE_ISSUE(6, qA0, qA1, fA);
        WAITL(6); TILE_BUILD(qB0, qB1, fB); TILE_ISSUE(7, qB0, qB1, fB);
        WAITL(6); TILE_BUILD(qC0, qC1, fC);
        WAITL(3); TILE_BUILD(qA0, qA1, fA);
        WAITL(0); TILE_BUILD(qB0, qB1, fB);     // drains iter's ds queue

        a = an; c = cn; l = ln;
    }

    // C/D layout (m89-verified): col = lane&15, row = (lane>>4)*4 + reg.
    // bin = row*16 + col. Reuse stage LDS as fold scratch (safe: all ds
    // ops drained by the final WAITL(0)).
    float* cnt_w = (float*)&s_iv[w][0][0];
    float* sum_w = (float*)&s_iv[w][1][0];
    const int row0 = (lane >> 4) << 2;
    const int colb = lane & 15;
    #pragma unroll
    for (int j = 0; j < 4; ++j) {
        cnt_w[(row0 + j) * 16 + colb] = accC[j];
        sum_w[(row0 + j) * 16 + colb] = accS[j];
    }
    __syncthreads();

    float cs = 0.0f, ss = 0.0f;
    #pragma unroll
    for (int ww = 0; ww < 4; ++ww) {
        cs += ((float*)&s_iv[ww][0][0])[tid];
        ss += ((float*)&s_iv[ww][1][0])[tid];
    }
    ws_slots[((size_t)(b * GRIDX + blockIdx.x)) * NLAB + tid] = ss + STEP * cs;
}

// ---------------------------------------------------------------------------
// Kernel 2: parallel slot reduction. Block r: batch = r/NPART, part = r%NPART;
// 256 threads = bins. Decode + sum GRIDX/NPART slots (coalesced 1KB rows).
// ---------------------------------------------------------------------------
__global__ __launch_bounds__(256) void reduce_kernel(
    const float* __restrict__ ws_slots, // [B*GRIDX][256]
    float* __restrict__ psum,           // [B*NPART][256]
    float* __restrict__ pcnt)           // [B*NPART][256]
{
    const int bin  = threadIdx.x;
    const int b    = blockIdx.x / NPART;
    const int part = blockIdx.x % NPART;
    const int per  = GRIDX / NPART;

    float cs = 0.0f, ss = 0.0f;
    for (int s = part * per; s < (part + 1) * per; ++s) {
        float v = ws_slots[((size_t)(b * GRIDX + s)) * NLAB + bin];
        float c = floorf(v * INV_STEP + 0.5f);   // exact count decode
        cs += c;
        ss += v - c * STEP;                      // packed fg sum
    }
    psum[(size_t)blockIdx.x * NLAB + bin] = ss;
    pcnt[(size_t)blockIdx.x * NLAB + bin] = cs;
}

// ---------------------------------------------------------------------------
// Kernel 3: fold partials, then masked softmin -> scalar loss.
// ---------------------------------------------------------------------------
__global__ __launch_bounds__(256) void scalar_kernel(
    const float* __restrict__ psum,     // [B*NPART][256]
    const float* __restrict__ pcnt,
    float* __restrict__ out)            // [1] loss
{
    __shared__ float s_fsum[BATCH][NLAB];
    __shared__ float s_fcnt[BATCH][NLAB];

    const int tid = threadIdx.x;        // 256 threads = bins

    for (int b = 0; b < BATCH; ++b) {
        float ss = 0.0f, cs = 0.0f;
        for (int p = 0; p < NPART; ++p) {
            ss += psum[(size_t)(b * NPART + p) * NLAB + tid];
            cs += pcnt[(size_t)(b * NPART + p) * NLAB + tid];
        }
        s_fsum[b][tid] = ss;
        s_fcnt[b][tid] = cs;
    }
    __syncthreads();

    if (tid < 64) {
        float total = 0.0f;
        float nbifs = 0.0f;
        if (tid >= 1) {  // bifs 1..63 (reference drops bif 0)
            for (int bb = 0; bb < BATCH; ++bb) {
                float means[3];
                bool  valid[3];
                int   nvalid = 0;
                for (int s = 0; s < 3; ++s) {
                    int lab = tid * 4 + 1 + s;   // stub s+1 (stub 0 dropped)
                    float cnt = s_fcnt[bb][lab];
                    float sum = s_fsum[bb][lab];
                    valid[s] = (cnt >= 1.0f);            // MIN_VOXELS = 1
                    means[s] = sum / fmaxf(cnt, 1.0f);
                    nvalid  += valid[s] ? 1 : 0;
                }
                float logits[3], m = -3e38f;
                for (int s = 0; s < 3; ++s) {
                    logits[s] = valid[s] ? (-means[s] / TEMP) : -1e9f;
                    m = fmaxf(m, logits[s]);
                }
                float e[3], se = 0.0f;
                for (int s = 0; s < 3; ++s) { e[s] = __expf(logits[s] - m); se += e[s]; }
                float score = 0.0f;
                for (int s = 0; s < 3; ++s) {
                    if (valid[s]) score += means[s] * (e[s] / se);
                }
                if (nvalid >= 2) {  // MIN_STUBS = 2
                    total += 1.0f - score;
                    nbifs += 1.0f;
                }
            }
        }
        for (int off = 32; off > 0; off >>= 1) {
            total += __shfl_down(total, off);
            nbifs += __shfl_down(nbifs, off);
        }
        if (tid == 0) {
            out[0] = (nbifs > 0.0f) ? (total / fmaxf(nbifs, 1.0f)) : 0.0f;
        }
    }
}

// ---------------------------------------------------------------------------
extern "C" void kernel_launch(void* const* d_in, const int* in_sizes, int n_in,
                              void* d_out, int out_size, void* d_ws, size_t ws_size,
                              hipStream_t stream) {
    const float* pred = (const float*)d_in[0];   // [B,C,D,H,W] fp32
    const float* lab  = (const float*)d_in[1];   // [B,1,D,H,W] fp32

    float* ws_slots = (float*)d_ws;                          // [B*GRIDX][256]
    float* psum = ws_slots + (size_t)BATCH * GRIDX * NLAB;   // [B*NPART][256]
    float* pcnt = psum + (size_t)BATCH * NPART * NLAB;       // [B*NPART][256]

    dim3 grid(GRIDX, BATCH);
    histo_kernel<<<grid, 256, 0, stream>>>(pred, lab, ws_slots);
    reduce_kernel<<<BATCH * NPART, 256, 0, stream>>>(ws_slots, psum, pcnt);
    scalar_kernel<<<1, 256, 0, stream>>>(psum, pcnt, (float*)d_out);
}